// Round 2
// baseline (142.747 us; speedup 1.0000x reference)
//
#include <hip/hip_runtime.h>
#include <hip/hip_bf16.h>
#include <math.h>

// ChamferLoss: pred [32,4096,3] f32, gt [32,4096,3] f32 -> scalar f32.
//
// min_m d2 = p2 + min_m (g2[m] - 2*dot)  -> 3 FMA + 1 min per pair (scalar).
//
// R6 post-mortem of R5: occupancy 17.5->28% yet VALUBusy pinned at 68% and
// dur unchanged -> NOT a latency/occupancy stall. Cycle arithmetic: 204
// cy/inner-iter measured vs 208 predicted if v_pk_fma_f32 occupies the fp32
// pipe 8 cycles (packed fp32 = HALF the scalar FLOP rate, not equal). The
// op_sel packing was a de-optimization: 24 pk x 8cy = 192 cy vs scalar
// 48 fma x 2cy = 96 cy for the same work. R6:
//  - Replace all v_pk_fma_f32 asm with plain fmaf/fminf chains ->
//    v_fma_f32 (2cy, m07-verified) + v_min3_f32. Floor 112 cy/iter.
//  - Queries stored un-packed (qx/qy/qz per query), targets read as
//    broadcast ds_read_b128 quads (-2x,-2y,-2z,g2) exactly as before.
//  - Everything else (grid 1024 = dir x batch x tsplit(8) x qsplit(2),
//    guarded atomicMin merge, 64-block finish) unchanged from R5.

#define TPB   256
#define QPT   8             // queries per thread; 2048 per block
#define NPTS  4096
#define TSPL  8             // target split (8 x 512)
#define QSPL  2             // query split  (2 x 2048)
#define TCH   (NPTS / TSPL) // 512 targets per block (8 KB LDS)
#define QCH   (NPTS / QSPL) // 2048 queries per block
#define NQTOT (2 * 32 * NPTS)

typedef float vf4 __attribute__((ext_vector_type(4)));

__global__ __launch_bounds__(TPB, 4) void chamfer_main(
    const float* __restrict__ pred,
    const float* __restrict__ gt,
    unsigned int* __restrict__ wsmin)
{
    // grid.x = 1024: dir (2) x batch (32) x tsplit (8) x qsplit (2)
    const int bx  = blockIdx.x;
    const int dir = bx >> 9;
    const int rem = bx & 511;
    const int b   = rem >> 4;
    const int sub = rem & 15;
    const int kt  = sub >> 1;
    const int qs  = sub & 1;

    const float* __restrict__ qbase = (dir ? gt : pred) + (size_t)b * NPTS * 3
                                      + (size_t)qs * QCH * 3;
    const float* __restrict__ tbase = (dir ? pred : gt) + (size_t)b * NPTS * 3;

    __shared__ vf4 sT[TCH];     // (-2x, -2y, -2z, x^2+y^2+z^2)  8 KB

    const int tid = threadIdx.x;

    // Stage this block's 512-target slice: 2 points per thread
    for (int j = tid; j < TCH; j += TPB) {
        const float* tp = tbase + (size_t)(kt * TCH + j) * 3;
        float x = tp[0], y = tp[1], z = tp[2];
        vf4 t; t[0] = -2.0f * x; t[1] = -2.0f * y; t[2] = -2.0f * z;
        t[3] = fmaf(x, x, fmaf(y, y, z * z));
        sT[j] = t;
    }

    // Load 8 queries per thread (raw coords; the -2 lives on the target side)
    float qx[QPT], qy[QPT], qz[QPT], mn[QPT];
#pragma unroll
    for (int i = 0; i < QPT; ++i) {
        const float* q = qbase + (size_t)(i * TPB + tid) * 3;
        qx[i] = q[0]; qy[i] = q[1]; qz[i] = q[2];
        mn[i] = 1e30f;
    }

    __syncthreads();

    // 2 targets x 8 queries per iter: 48 v_fma_f32 (2cy) + 8 v_min3_f32
    // per 2 broadcast ds_read_b128. 16 independent 3-deep fma chains.
#pragma unroll 2
    for (int j = 0; j < TCH; j += 2) {
        const vf4 G0 = sT[j];
        const vf4 G1 = sT[j + 1];
#pragma unroll
        for (int i = 0; i < QPT; ++i) {
            float d0 = fmaf(qx[i], G0[0],
                       fmaf(qy[i], G0[1],
                       fmaf(qz[i], G0[2], G0[3])));
            float d1 = fmaf(qx[i], G1[0],
                       fmaf(qy[i], G1[1],
                       fmaf(qz[i], G1[2], G1[3])));
            mn[i] = fminf(fminf(d0, d1), mn[i]);   // v_min3_f32
        }
    }

    // d2 = p2 + min, clamp >=1e-12 (positive -> uint order == float order);
    // merge across sibling tsplit blocks with atomicMin, guarded by a plain
    // load (values only decrease -> stale read is safe-conservative).
    unsigned int* wq = wsmin + (size_t)(dir * 32 + b) * NPTS + (size_t)qs * QCH;
#pragma unroll
    for (int i = 0; i < QPT; ++i) {
        float p2 = fmaf(qx[i], qx[i], fmaf(qy[i], qy[i], qz[i] * qz[i]));
        float d2 = fmaxf(mn[i] + p2, 1e-12f);
        unsigned int mine = __float_as_uint(d2);
        if (mine < wq[i * TPB + tid])
            atomicMin(&wq[i * TPB + tid], mine);
    }
}

// sqrt + mean over all 262144 query mins, accumulate into out[0].
// 64 blocks x 16 elems/thread -> only 64 serialized atomicAdds on out[0].
#define FIN_EPT 16
__global__ __launch_bounds__(TPB) void chamfer_finish(
    const unsigned int* __restrict__ wsmin,
    float* __restrict__ out)
{
    __shared__ float swave[TPB / 64];
    const int tid  = threadIdx.x;
    const int base = blockIdx.x * (TPB * FIN_EPT) + tid;

    float s = 0.0f;
#pragma unroll
    for (int r = 0; r < FIN_EPT; ++r) {
        float d2 = __uint_as_float(wsmin[base + r * TPB]);
        s += sqrtf(d2);
    }

#pragma unroll
    for (int off = 32; off > 0; off >>= 1)
        s += __shfl_down(s, off, 64);
    const int wid = tid >> 6, lane = tid & 63;
    if (lane == 0) swave[wid] = s;
    __syncthreads();
    if (tid == 0) {
        float tot = swave[0] + swave[1] + swave[2] + swave[3];
        atomicAdd(out, tot * (1.0f / 131072.0f));
    }
}

extern "C" void kernel_launch(void* const* d_in, const int* in_sizes, int n_in,
                              void* d_out, int out_size, void* d_ws, size_t ws_size,
                              hipStream_t stream)
{
    const float* pred = (const float*)d_in[0];
    const float* gt   = (const float*)d_in[1];
    float* out        = (float*)d_out;
    unsigned int* wsmin = (unsigned int*)d_ws;

    // Identity for uint atomicMin: 0xFFFFFFFF. Zero the scalar output.
    hipMemsetAsync(d_ws, 0xFF, (size_t)NQTOT * sizeof(unsigned int), stream);
    hipMemsetAsync(d_out, 0, sizeof(float), stream);

    chamfer_main<<<dim3(1024), dim3(TPB), 0, stream>>>(pred, gt, wsmin);
    chamfer_finish<<<dim3(NQTOT / (TPB * FIN_EPT)), dim3(TPB), 0, stream>>>(wsmin, out);
}